// Round 7
// baseline (401.157 us; speedup 1.0000x reference)
//
#include <hip/hip_runtime.h>
#include <hip/hip_bf16.h>

#define HIDDEN 1024
#define INTER 2048
#define NE 8
#define GS 128
#define TOKENS 4096
#define MAXROWS 9216  // 8192 routed rows + 8*128 padding capacity
#define MAXTILES 72   // 128-row tiles
#define MAXT256 40    // 256-row tiles (reserved)

typedef __bf16 bf16x8 __attribute__((ext_vector_type(8)));
typedef float f32x4 __attribute__((ext_vector_type(4)));

// ---- ws layout v4 (bytes) ----
#define OFF_TOPKI 0u               // int[4096][2]
#define OFF_TOPKW 32768u           // float[4096][2]
#define OFF_CTRL  65536u           // int[32]
#define OFF_TOK   66048u           // int[MAXROWS]
#define OFF_SLOT  102912u          // int[TOKENS*2]
#define OFF_TILE  135680u          // int[MAXTILES]
#define OFF_T256  136192u          // int[MAXT256]
#define OFF_V256  136448u          // int[MAXT256]
#define OFF_XB    139776u          // bf16[TOKENS+1][HIDDEN]  (row TOKENS = zeros)
#define OFF_A     8530432u         // bf16[MAXROWS][INTER]
#define OFF_Y0    46279168u        // bf16[MAXROWS][HIDDEN]
#define OFF_Y1    (OFF_Y0 + 18874368u)

__device__ __forceinline__ unsigned short f2bf(float f) {
  union { float f; unsigned int u; } v; v.f = f;
  unsigned int r = (v.u + 0x7FFFu + ((v.u >> 16) & 1u)) >> 16;
  return (unsigned short)r;
}
__device__ __forceinline__ float bf2f(unsigned int u) {
  union { unsigned int u; float f; } v; v.u = u << 16;
  return v.f;
}
__device__ __forceinline__ unsigned int pack2(unsigned short lo, unsigned short hi) {
  return (unsigned int)lo | ((unsigned int)hi << 16);
}

// async global->LDS, 16B per lane. LDS dest is wave-uniform base + lane*16.
typedef const __attribute__((address_space(1))) unsigned int GAS;
typedef __attribute__((address_space(3))) unsigned int LAS;
__device__ __forceinline__ void gload16(const unsigned short* g, unsigned short* l) {
  __builtin_amdgcn_global_load_lds((GAS*)g, (LAS*)l, 16, 0, 0);
}

// ---- in-register int4 dequant: 4 packed int32 -> 8 bf16 (k-order) ----------
// f32 bits (0x43000000 | q<<16) == 128+q exactly (q in [0,15]);
// fma(128+q, s, -136*s) = (q-8)*s, single rounding; v_cvt_pk_bf16_f32 RNE-packs.
__device__ __forceinline__ uint4 deq8(int4 p, float s, float c) {
  unsigned int pv[4] = { (unsigned int)p.x, (unsigned int)p.y,
                         (unsigned int)p.z, (unsigned int)p.w };
  unsigned int ov[4];
#pragma unroll
  for (int j = 0; j < 4; j++) {
    unsigned int v = pv[j];
    float flo = __uint_as_float(0x43000000u | ((v & 15u) << 16));
    float fhi = __uint_as_float(0x43000000u | ((v << 12) & 0x000F0000u));
    float lo = __builtin_fmaf(flo, s, c);
    float hi = __builtin_fmaf(fhi, s, c);
    unsigned int pk;
    asm("v_cvt_pk_bf16_f32 %0, %1, %2" : "=v"(pk) : "v"(lo), "v"(hi));
    ov[j] = pk;
  }
  uint4 o; o.x = ov[0]; o.y = ov[1]; o.z = ov[2]; o.w = ov[3];
  return o;
}

// ---- prep v3: router + xconv fused | zero-row.  Weight dequant DELETED. ----
__global__ __launch_bounds__(256) void k_prep(const float* __restrict__ x,
    const float* __restrict__ rw, int* __restrict__ topki, float* __restrict__ topkw,
    unsigned short* __restrict__ xb) {
  int bid = blockIdx.x, tid = threadIdx.x;
  if (bid == 1024) {
    uint2 z; z.x = 0u; z.y = 0u;
    *reinterpret_cast<uint2*>(xb + (size_t)TOKENS * HIDDEN + tid * 4) = z;
    return;
  }
  int wave = tid >> 6, lane = tid & 63;
  int t = bid * 4 + wave;
  const float* xr = x + (size_t)t * HIDDEN;
  float acc[NE];
#pragma unroll
  for (int e = 0; e < NE; e++) acc[e] = 0.f;
#pragma unroll
  for (int j = 0; j < 4; j++) {
    int col = j * 256 + lane * 4;
    float4 xv = *reinterpret_cast<const float4*>(xr + col);
    uint2 o;
    o.x = pack2(f2bf(xv.x), f2bf(xv.y));
    o.y = pack2(f2bf(xv.z), f2bf(xv.w));
    *reinterpret_cast<uint2*>(xb + (size_t)t * HIDDEN + col) = o;
#pragma unroll
    for (int e = 0; e < NE; e++) {
      float4 wv = *reinterpret_cast<const float4*>(rw + e * HIDDEN + col);
      acc[e] += xv.x * wv.x + xv.y * wv.y + xv.z * wv.z + xv.w * wv.w;
    }
  }
#pragma unroll
  for (int e = 0; e < NE; e++) {
    float v = acc[e];
    for (int off = 32; off > 0; off >>= 1) v += __shfl_down(v, off, 64);
    acc[e] = v;
  }
  if (lane == 0) {
    int b0 = 0; float s0 = acc[0];
#pragma unroll
    for (int e = 1; e < NE; e++) if (acc[e] > s0) { s0 = acc[e]; b0 = e; }
    int b1 = -1; float s1 = -3.0e38f;
#pragma unroll
    for (int e = 0; e < NE; e++) if (e != b0 && acc[e] > s1) { s1 = acc[e]; b1 = e; }
    float w0 = 1.f / (1.f + __expf(s1 - s0));
    topki[t * 2] = b0; topki[t * 2 + 1] = b1;
    topkw[t * 2] = w0; topkw[t * 2 + 1] = 1.f - w0;
  }
}

// ------- route2 (1 block): hist + offsets + tilemaps + pad fill + scatter ---
__global__ __launch_bounds__(256) void k_route2(const int* __restrict__ topki,
    int* __restrict__ ctrl, int* __restrict__ tok, int* __restrict__ slots,
    int* __restrict__ tilemap, int* __restrict__ tile256, int* __restrict__ valid256) {
  __shared__ int h[NE], off[NE], cnt[NE];
  int tid = threadIdx.x;
  if (tid < NE) h[tid] = 0;
  __syncthreads();
  for (int i = tid; i < TOKENS * 2; i += 256) atomicAdd(&h[topki[i]], 1);
  __syncthreads();
  if (tid == 0) {
    int run = 0, t = 0, t2 = 0;
    for (int e = 0; e < NE; e++) {
      int c = h[e];
      ctrl[e] = c; ctrl[16 + e] = run; off[e] = run;
      int pc = (c + 127) & ~127;
      int m = pc >> 7;
      for (int mt = 0; mt < m; mt++) tilemap[t++] = (e << 20) | (run + mt * 128);
      int n2 = (m + 1) >> 1;
      for (int i2 = 0; i2 < n2; i2++) {
        int st = i2 * 256;
        if (st + 256 > pc) st = (pc >= 256) ? (pc - 256) : 0;
        tile256[t2] = (e << 20) | (run + st);
        int v = pc - st; valid256[t2] = (v < 256) ? v : 256;
        t2++;
      }
      run += pc;
    }
    ctrl[24] = run; ctrl[25] = t; ctrl[26] = t2;
  }
  __syncthreads();
#pragma unroll
  for (int e = 0; e < NE; e++) {
    int c = h[e], pc = (c + 127) & ~127;
    for (int i = c + tid; i < pc; i += 256) tok[off[e] + i] = -1;
  }
  if (tid < NE) cnt[tid] = off[tid];
  __syncthreads();
  for (int i = tid; i < TOKENS * 2; i += 256) {
    int e = topki[i];
    int p = atomicAdd(&cnt[e], 1);
    tok[p] = i >> 1;
    slots[i] = p;
  }
}

// --------------- GEMM1: h = gather(xb) @ deq(w1)^T, silu(gate)*up -> a -----
// Fused dequant + dbuf LDS + one __syncthreads/step (r6), PLUS:
//  - group scales hoisted to a 2-reg rotating window, prefetched 1 group ahead
//    (removes 2 scattered dword loads per thread per K-step)
//  - packed-B loads pipelined 2 steps deep (a_p = data for kt+1, loaded kt-1)
__global__ __launch_bounds__(256) void k_gemm1(
    const unsigned short* __restrict__ xb, const int* __restrict__ w1,
    const float* __restrict__ w1s, const int* __restrict__ ctrl,
    const int* __restrict__ tilemap, const int* __restrict__ tok,
    unsigned short* __restrict__ a_out) {
  __shared__ unsigned short sA[2 * 128 * 32];   // 16 KB (2 buf)
  __shared__ unsigned short sBg[2 * 64 * 32];   // 8 KB
  __shared__ unsigned short sBu[2 * 64 * 32];   // 8 KB
  int bid = blockIdx.x, tid = threadIdx.x;
  int nt = bid & 31, tile = bid >> 5;
  if (tile >= ctrl[25]) return;
  int tm = tilemap[tile];
  int e = tm >> 20, row0 = tm & 0xFFFFF;
  int n0 = nt * 64;
  int wave = tid >> 6, lane = tid & 63;
  int ln = lane & 15, quad = lane >> 4;
  int wr = (wave & 1) * 64, wc = (wave >> 1) * 32;

  int srow = tid >> 2;
  int gcb = (tid & 3) ^ ((srow >> 1) & 3);   // swizzle pre-applied on source
  int scol = gcb * 8;
  int t0 = tok[row0 + srow];
  int t1 = tok[row0 + 64 + srow];
  const unsigned short* gA0 = xb + (size_t)(t0 < 0 ? TOKENS : t0) * HIDDEN + scol;
  const unsigned short* gA1 = xb + (size_t)(t1 < 0 ? TOKENS : t1) * HIDDEN + scol;
  const int* gPg = w1 + (((size_t)e * 4096 + n0 + srow) << 9) + gcb * 4;  // 512 i32/row
  const int* gPu = gPg + ((size_t)2048 << 9);
  const float* sWg = w1s + ((size_t)e * 4096 + n0 + srow) * 8;
  const float* sWu = sWg + 2048 * 8;

  // ---- prologue ----
  float sgc = sWg[0], suc = sWu[0];      // scale window: current group
  float sgn = sWg[1], sun = sWu[1];      // next group (prefetched)
  gload16(gA0, sA + tid * 8);
  gload16(gA1, sA + 64 * 32 + tid * 8);
  int4 c_pg = *reinterpret_cast<const int4*>(gPg);        // packed step 0
  int4 c_pu = *reinterpret_cast<const int4*>(gPu);
  int4 a_pg = *reinterpret_cast<const int4*>(gPg + 16);   // packed step 1
  int4 a_pu = *reinterpret_cast<const int4*>(gPu + 16);
  *reinterpret_cast<uint4*>(sBg + tid * 8) = deq8(c_pg, sgc, -136.f * sgc);
  *reinterpret_cast<uint4*>(sBu + tid * 8) = deq8(c_pu, suc, -136.f * suc);
  __syncthreads();

  f32x4 aG[4][2] = {}, aU[4][2] = {};
  for (int g = 0; g < 8; g++) {
#pragma unroll
    for (int kk = 0; kk < 4; kk++) {
      int kt = g * 4 + kk;
      int buf = kt & 1, nb = buf ^ 1;
      int kn1 = (kt + 1 < 32) ? kt + 1 : 31;   // step staged into nb this iter
      int kn2 = (kt + 2 < 32) ? kt + 2 : 31;   // packed loaded this iter
      // issue next-step A DMA + next-next packed loads (2-deep cover)
      gload16(gA0 + kn1 * 32, sA + nb * 4096 + tid * 8);
      gload16(gA1 + kn1 * 32, sA + nb * 4096 + 64 * 32 + tid * 8);
      int4 n_pg = *reinterpret_cast<const int4*>(gPg + kn2 * 16);
      int4 n_pu = *reinterpret_cast<const int4*>(gPu + kn2 * 16);
      // current-step fragments + MFMA
      const unsigned short* Ab = sA + buf * 4096;
      const unsigned short* Bg = sBg + buf * 2048;
      const unsigned short* Bu = sBu + buf * 2048;
      bf16x8 af[4], bg[2], bu[2];
#pragma unroll
      for (int m = 0; m < 4; m++) {
        int ar = wr + m * 16 + ln;
        af[m] = *reinterpret_cast<const bf16x8*>(&Ab[ar * 32 + (quad ^ ((ar >> 1) & 3)) * 8]);
      }
#pragma unroll
      for (int n = 0; n < 2; n++) {
        int br = wc + n * 16 + ln;
        int bo = br * 32 + (quad ^ ((br >> 1) & 3)) * 8;
        bg[n] = *reinterpret_cast<const bf16x8*>(&Bg[bo]);
        bu[n] = *reinterpret_cast<const bf16x8*>(&Bu[bo]);
      }
#pragma unroll
      for (int m = 0; m < 4; m++)
#pragma unroll
        for (int n = 0; n < 2; n++) {
          aG[m][n] = __builtin_amdgcn_mfma_f32_16x16x32_bf16(af[m], bg[n], aG[m][n], 0, 0, 0);
          aU[m][n] = __builtin_amdgcn_mfma_f32_16x16x32_bf16(af[m], bu[n], aU[m][n], 0, 0, 0);
        }
      // dequant step kt+1 (data loaded 2 steps ago); kk==3 crosses group bound
      float sG = (kk == 3) ? sgn : sgc;
      float sU = (kk == 3) ? sun : suc;
      *reinterpret_cast<uint4*>(sBg + nb * 2048 + tid * 8) = deq8(a_pg, sG, -136.f * sG);
      *reinterpret_cast<uint4*>(sBu + nb * 2048 + tid * 8) = deq8(a_pu, sU, -136.f * sU);
      a_pg = n_pg; a_pu = n_pu;
      __syncthreads();
    }
    // rotate scale window; prefetch group g+2 (used 4+ steps later)
    sgc = sgn; suc = sun;
    int gn = (g + 2 < 8) ? g + 2 : 7;
    sgn = sWg[gn]; sun = sWu[gn];
  }
#pragma unroll
  for (int m = 0; m < 4; m++)
#pragma unroll
    for (int n = 0; n < 2; n++) {
      int col = n0 + wc + n * 16 + ln;
#pragma unroll
      for (int r = 0; r < 4; r++) {
        float g = aG[m][n][r], u = aU[m][n][r];
        float act = (g / (1.f + __expf(-g))) * u;
        int row = row0 + wr + m * 16 + quad * 4 + r;
        a_out[(size_t)row * INTER + col] = f2bf(act);
      }
    }
}

// ------- GEMM2 split-K x2: y[kp][slot] = a[:,kp*1024:+1024] @ deq(w2)^T ----
// Same dbuf + hoisted-scales + 2-deep packed pipeline as gemm1.
__global__ __launch_bounds__(256) void k_gemm2(
    const unsigned short* __restrict__ a_in, const int* __restrict__ w2,
    const float* __restrict__ w2s, const int* __restrict__ ctrl,
    const int* __restrict__ tilemap, unsigned short* __restrict__ y) {
  __shared__ unsigned short sA[2 * 128 * 32];   // 16 KB
  __shared__ unsigned short sB[2 * 128 * 32];   // 16 KB
  int bid = blockIdx.x, tid = threadIdx.x;
  int kp = bid & 1, nt = (bid >> 1) & 7, tile = bid >> 4;
  if (tile >= ctrl[25]) return;
  int tm = tilemap[tile];
  int e = tm >> 20, row0 = tm & 0xFFFFF;
  int n0 = nt * 128;
  int wave = tid >> 6, lane = tid & 63;
  int ln = lane & 15, quad = lane >> 4;
  int wr = (wave & 1) * 64, wc = (wave >> 1) * 64;

  int srow = tid >> 2;
  int gcb = (tid & 3) ^ ((srow >> 1) & 3);
  int scol = gcb * 8;
  int kbase = kp * (INTER / 2);
  const unsigned short* gA0 = a_in + (size_t)(row0 + srow) * INTER + kbase + scol;
  const unsigned short* gA1 = gA0 + (size_t)64 * INTER;
  const int* gP0 = w2 + ((size_t)e * 1024 + n0 + srow) * 1024 + (kbase >> 1) + gcb * 4;
  const int* gP1 = gP0 + (size_t)64 * 1024;
  const float* sW0 = w2s + ((size_t)e * 1024 + n0 + srow) * 16 + kp * 8;
  const float* sW1 = sW0 + 64 * 16;

  // ---- prologue ----
  float s0c = sW0[0], s1c = sW1[0];
  float s0n = sW0[1], s1n = sW1[1];
  gload16(gA0, sA + tid * 8);
  gload16(gA1, sA + 64 * 32 + tid * 8);
  int4 c_p0 = *reinterpret_cast<const int4*>(gP0);
  int4 c_p1 = *reinterpret_cast<const int4*>(gP1);
  int4 a_p0 = *reinterpret_cast<const int4*>(gP0 + 16);
  int4 a_p1 = *reinterpret_cast<const int4*>(gP1 + 16);
  *reinterpret_cast<uint4*>(sB + tid * 8) = deq8(c_p0, s0c, -136.f * s0c);
  *reinterpret_cast<uint4*>(sB + 64 * 32 + tid * 8) = deq8(c_p1, s1c, -136.f * s1c);
  __syncthreads();

  f32x4 acc[4][4] = {};
  for (int g = 0; g < 8; g++) {
#pragma unroll
    for (int kk = 0; kk < 4; kk++) {
      int kt = g * 4 + kk;
      int buf = kt & 1, nb = buf ^ 1;
      int kn1 = (kt + 1 < 32) ? kt + 1 : 31;
      int kn2 = (kt + 2 < 32) ? kt + 2 : 31;
      gload16(gA0 + kn1 * 32, sA + nb * 4096 + tid * 8);
      gload16(gA1 + kn1 * 32, sA + nb * 4096 + 64 * 32 + tid * 8);
      int4 n_p0 = *reinterpret_cast<const int4*>(gP0 + kn2 * 16);
      int4 n_p1 = *reinterpret_cast<const int4*>(gP1 + kn2 * 16);
      const unsigned short* Ab = sA + buf * 4096;
      const unsigned short* Bb = sB + buf * 4096;
      bf16x8 af[4], bf_[4];
#pragma unroll
      for (int m = 0; m < 4; m++) {
        int ar = wr + m * 16 + ln;
        af[m] = *reinterpret_cast<const bf16x8*>(&Ab[ar * 32 + (quad ^ ((ar >> 1) & 3)) * 8]);
      }
#pragma unroll
      for (int n = 0; n < 4; n++) {
        int br = wc + n * 16 + ln;
        bf_[n] = *reinterpret_cast<const bf16x8*>(&Bb[br * 32 + (quad ^ ((br >> 1) & 3)) * 8]);
      }
#pragma unroll
      for (int m = 0; m < 4; m++)
#pragma unroll
        for (int n = 0; n < 4; n++)
          acc[m][n] = __builtin_amdgcn_mfma_f32_16x16x32_bf16(af[m], bf_[n], acc[m][n], 0, 0, 0);
      float sL = (kk == 3) ? s0n : s0c;
      float sH = (kk == 3) ? s1n : s1c;
      *reinterpret_cast<uint4*>(sB + nb * 4096 + tid * 8) = deq8(a_p0, sL, -136.f * sL);
      *reinterpret_cast<uint4*>(sB + nb * 4096 + 64 * 32 + tid * 8) = deq8(a_p1, sH, -136.f * sH);
      a_p0 = n_p0; a_p1 = n_p1;
      __syncthreads();
    }
    s0c = s0n; s1c = s1n;
    int gn = (g + 2 < 8) ? g + 2 : 7;
    s0n = sW0[gn]; s1n = sW1[gn];
  }
  unsigned short* yk = y + (size_t)kp * MAXROWS * HIDDEN;
#pragma unroll
  for (int m = 0; m < 4; m++)
#pragma unroll
    for (int n = 0; n < 4; n++) {
      int col = n0 + wc + n * 16 + ln;
#pragma unroll
      for (int r = 0; r < 4; r++) {
        int row = row0 + wr + m * 16 + quad * 4 + r;
        yk[(size_t)row * HIDDEN + col] = f2bf(acc[m][n][r]);
      }
    }
}

// ------- combine: out[t] = g0*(y0[s0]+y1[s0]) + g1*(y0[s1]+y1[s1]) ---------
__global__ __launch_bounds__(256) void k_combine(const unsigned short* __restrict__ y,
    const int* __restrict__ slots, const float* __restrict__ topkw,
    float* __restrict__ out) {
  int t = blockIdx.x;
  int c = threadIdx.x * 4;
  int s0 = slots[t * 2], s1 = slots[t * 2 + 1];
  float g0 = topkw[t * 2], g1 = topkw[t * 2 + 1];
  const unsigned short* y1 = y + (size_t)MAXROWS * HIDDEN;
  uint2 a0 = *reinterpret_cast<const uint2*>(y  + (size_t)s0 * HIDDEN + c);
  uint2 a1 = *reinterpret_cast<const uint2*>(y1 + (size_t)s0 * HIDDEN + c);
  uint2 b0 = *reinterpret_cast<const uint2*>(y  + (size_t)s1 * HIDDEN + c);
  uint2 b1 = *reinterpret_cast<const uint2*>(y1 + (size_t)s1 * HIDDEN + c);
  float4 o;
  o.x = g0 * (bf2f(a0.x & 0xffffu) + bf2f(a1.x & 0xffffu))
      + g1 * (bf2f(b0.x & 0xffffu) + bf2f(b1.x & 0xffffu));
  o.y = g0 * (bf2f(a0.x >> 16) + bf2f(a1.x >> 16))
      + g1 * (bf2f(b0.x >> 16) + bf2f(b1.x >> 16));
  o.z = g0 * (bf2f(a0.y & 0xffffu) + bf2f(a1.y & 0xffffu))
      + g1 * (bf2f(b0.y & 0xffffu) + bf2f(b1.y & 0xffffu));
  o.w = g0 * (bf2f(a0.y >> 16) + bf2f(a1.y >> 16))
      + g1 * (bf2f(b0.y >> 16) + bf2f(b1.y >> 16));
  *reinterpret_cast<float4*>(out + (size_t)t * HIDDEN + c) = o;
}

extern "C" void kernel_launch(void* const* d_in, const int* in_sizes, int n_in,
                              void* d_out, int out_size, void* d_ws, size_t ws_size,
                              hipStream_t stream) {
  const float* x   = (const float*)d_in[0];
  const float* rw  = (const float*)d_in[1];
  const int*   w1  = (const int*)d_in[2];
  const float* w1s = (const float*)d_in[3];
  const int*   w2  = (const int*)d_in[4];
  const float* w2s = (const float*)d_in[5];
  float* out = (float*)d_out;
  char* ws = (char*)d_ws;

  int*   topki = (int*)(ws + OFF_TOPKI);
  float* topkw = (float*)(ws + OFF_TOPKW);
  int*   ctrl  = (int*)(ws + OFF_CTRL);
  int*   tok   = (int*)(ws + OFF_TOK);
  int*   slots = (int*)(ws + OFF_SLOT);
  int*   tilemap = (int*)(ws + OFF_TILE);
  int*   tile256 = (int*)(ws + OFF_T256);
  int*   valid256 = (int*)(ws + OFF_V256);
  unsigned short* xb  = (unsigned short*)(ws + OFF_XB);
  unsigned short* a   = (unsigned short*)(ws + OFF_A);
  unsigned short* y   = (unsigned short*)(ws + OFF_Y0);  // y1 = y + MAXROWS*HIDDEN

  k_prep<<<1025, 256, 0, stream>>>(x, rw, topki, topkw, xb);
  k_route2<<<1, 256, 0, stream>>>(topki, ctrl, tok, slots, tilemap, tile256, valid256);
  k_gemm1<<<32 * MAXTILES, 256, 0, stream>>>(xb, w1, w1s, ctrl, tilemap, tok, a);
  k_gemm2<<<16 * MAXTILES, 256, 0, stream>>>(a, w2, w2s, ctrl, tilemap, y);
  k_combine<<<TOKENS, 256, 0, stream>>>(y, slots, topkw, out);
}

// Round 8
// 341.318 us; speedup vs baseline: 1.1753x; 1.1753x over previous
//
#include <hip/hip_runtime.h>
#include <hip/hip_bf16.h>

#define HIDDEN 1024
#define INTER 2048
#define NE 8
#define GS 128
#define TOKENS 4096
#define MAXROWS 9216  // 8192 routed rows + 8*128 padding capacity
#define MAXTILES 72   // 128-row tiles
#define MAXT256 40    // 256-row tiles (reserved)

typedef __bf16 bf16x8 __attribute__((ext_vector_type(8)));
typedef float f32x4 __attribute__((ext_vector_type(4)));
typedef int i32x4 __attribute__((ext_vector_type(4)));
typedef unsigned int u32x4 __attribute__((ext_vector_type(4)));

// ---- ws layout v3 (bytes) ----
#define OFF_TOPKI 0u               // int[4096][2]
#define OFF_TOPKW 32768u           // float[4096][2]
#define OFF_CTRL  65536u           // int[32]
#define OFF_TOK   66048u           // int[MAXROWS]
#define OFF_SLOT  102912u          // int[TOKENS*2]
#define OFF_TILE  135680u          // int[MAXTILES]
#define OFF_T256  136192u          // int[MAXT256]
#define OFF_V256  136448u          // int[MAXT256]
#define OFF_XB    139776u          // bf16[TOKENS+1][HIDDEN]  (row TOKENS = zeros)
#define OFF_A     8530432u         // bf16[MAXROWS][INTER]
#define OFF_W1D   46279168u        // bf16[NE][4096][HIDDEN]  (dead after gemm1)
#define OFF_W2D   113388032u       // bf16[NE][1024][INTER]   -> 146942464 total
#define OFF_Y0    OFF_W1D          // bf16[MAXROWS][HIDDEN]   (aliases dead w1d)
#define OFF_Y1    (OFF_W1D + 18874368u)

__device__ __forceinline__ unsigned short f2bf(float f) {
  union { float f; unsigned int u; } v; v.f = f;
  unsigned int r = (v.u + 0x7FFFu + ((v.u >> 16) & 1u)) >> 16;
  return (unsigned short)r;
}
__device__ __forceinline__ float bf2f(unsigned int u) {
  union { unsigned int u; float f; } v; v.u = u << 16;
  return v.f;
}
__device__ __forceinline__ unsigned int pack2(unsigned short lo, unsigned short hi) {
  return (unsigned int)lo | ((unsigned int)hi << 16);
}

// async global->LDS, 16B per lane. LDS dest is wave-uniform base + lane*16.
typedef const __attribute__((address_space(1))) unsigned int GAS;
typedef __attribute__((address_space(3))) unsigned int LAS;
__device__ __forceinline__ void gload16(const unsigned short* g, unsigned short* l) {
  __builtin_amdgcn_global_load_lds((GAS*)g, (LAS*)l, 16, 0, 0);
}

// ---- prep: router+xconv fused | deq1 x4 | deq2 x4 | zero-row ---------------
// Dequant paths use NON-TEMPORAL loads+stores: packed w1/w2 are read once and
// never again; w1d/w2d are streamed out (avoid L2 write round-trip / RFO).
// block ranges: [0,1024) router(+xb), [1024,5120) deq1, [5120,7168) deq2,
//               7168 zero-row.
__global__ __launch_bounds__(256) void k_prep(const float* __restrict__ x,
    const float* __restrict__ rw, int* __restrict__ topki, float* __restrict__ topkw,
    const int* __restrict__ w1, const float* __restrict__ w1s,
    unsigned short* __restrict__ w1d,
    const int* __restrict__ w2, const float* __restrict__ w2s,
    unsigned short* __restrict__ w2d, unsigned short* __restrict__ xb) {
  int bid = blockIdx.x, tid = threadIdx.x;
  if (bid == 7168) {
    uint2 z; z.x = 0u; z.y = 0u;
    *reinterpret_cast<uint2*>(xb + (size_t)TOKENS * HIDDEN + tid * 4) = z;
    return;
  }
  if (bid >= 5120) {
    // ---- deq2: 4 chunks x 4 int32, block covers 4096 int32 ----
    size_t base = (size_t)(bid - 5120) * 4096 + tid * 4;
    i32x4 p[4];
#pragma unroll
    for (int c = 0; c < 4; c++)
      p[c] = __builtin_nontemporal_load(reinterpret_cast<const i32x4*>(w2 + base + c * 1024));
#pragma unroll
    for (int c = 0; c < 4; c++) {
      size_t i4 = base + c * 1024;
      int r = (int)(i4 >> 10);
      int i = (int)(i4 & 1023);
      float s = w2s[r * 16 + (i >> 6)];
      u32x4 o;
#pragma unroll
      for (int j = 0; j < 4; j++) {
        int pv = p[c][j];
        float lo = (float)((pv & 15) - 8) * s;
        float hi = (float)(((pv >> 4) & 15) - 8) * s;
        o[j] = pack2(f2bf(lo), f2bf(hi));
      }
      __builtin_nontemporal_store(o, reinterpret_cast<u32x4*>(w2d + 2 * i4));
    }
    return;
  }
  if (bid >= 1024) {
    // ---- deq1: 4 chunks x 4 int32, block covers 4096 int32 ----
    size_t base = (size_t)(bid - 1024) * 4096 + tid * 4;
    i32x4 p[4];
#pragma unroll
    for (int c = 0; c < 4; c++)
      p[c] = __builtin_nontemporal_load(reinterpret_cast<const i32x4*>(w1 + base + c * 1024));
#pragma unroll
    for (int c = 0; c < 4; c++) {
      size_t i4 = base + c * 1024;
      int r = (int)(i4 >> 9);
      int i = (int)(i4 & 511);
      float s = w1s[r * 8 + (i >> 6)];
      u32x4 o;
#pragma unroll
      for (int j = 0; j < 4; j++) {
        int pv = p[c][j];
        float lo = (float)((pv & 15) - 8) * s;
        float hi = (float)(((pv >> 4) & 15) - 8) * s;
        o[j] = pack2(f2bf(lo), f2bf(hi));
      }
      __builtin_nontemporal_store(o, reinterpret_cast<u32x4*>(w1d + 2 * i4));
    }
    return;
  }
  // ---- router + xb conversion (fused; x read once) ----
  int wave = tid >> 6, lane = tid & 63;
  int t = bid * 4 + wave;
  const float* xr = x + (size_t)t * HIDDEN;
  float acc[NE];
#pragma unroll
  for (int e = 0; e < NE; e++) acc[e] = 0.f;
#pragma unroll
  for (int j = 0; j < 4; j++) {
    int col = j * 256 + lane * 4;
    float4 xv = *reinterpret_cast<const float4*>(xr + col);
    uint2 o;
    o.x = pack2(f2bf(xv.x), f2bf(xv.y));
    o.y = pack2(f2bf(xv.z), f2bf(xv.w));
    *reinterpret_cast<uint2*>(xb + (size_t)t * HIDDEN + col) = o;
#pragma unroll
    for (int e = 0; e < NE; e++) {
      float4 wv = *reinterpret_cast<const float4*>(rw + e * HIDDEN + col);
      acc[e] += xv.x * wv.x + xv.y * wv.y + xv.z * wv.z + xv.w * wv.w;
    }
  }
#pragma unroll
  for (int e = 0; e < NE; e++) {
    float v = acc[e];
    for (int off = 32; off > 0; off >>= 1) v += __shfl_down(v, off, 64);
    acc[e] = v;
  }
  if (lane == 0) {
    int b0 = 0; float s0 = acc[0];
#pragma unroll
    for (int e = 1; e < NE; e++) if (acc[e] > s0) { s0 = acc[e]; b0 = e; }
    int b1 = -1; float s1 = -3.0e38f;
#pragma unroll
    for (int e = 0; e < NE; e++) if (e != b0 && acc[e] > s1) { s1 = acc[e]; b1 = e; }
    float w0 = 1.f / (1.f + __expf(s1 - s0));
    topki[t * 2] = b0; topki[t * 2 + 1] = b1;
    topkw[t * 2] = w0; topkw[t * 2 + 1] = 1.f - w0;
  }
}

// ------- route2 (1 block): hist + offsets + tilemaps + pad fill + scatter ---
__global__ __launch_bounds__(256) void k_route2(const int* __restrict__ topki,
    int* __restrict__ ctrl, int* __restrict__ tok, int* __restrict__ slots,
    int* __restrict__ tilemap, int* __restrict__ tile256, int* __restrict__ valid256) {
  __shared__ int h[NE], off[NE], cnt[NE];
  int tid = threadIdx.x;
  if (tid < NE) h[tid] = 0;
  __syncthreads();
  for (int i = tid; i < TOKENS * 2; i += 256) atomicAdd(&h[topki[i]], 1);
  __syncthreads();
  if (tid == 0) {
    int run = 0, t = 0, t2 = 0;
    for (int e = 0; e < NE; e++) {
      int c = h[e];
      ctrl[e] = c; ctrl[16 + e] = run; off[e] = run;
      int pc = (c + 127) & ~127;
      int m = pc >> 7;
      for (int mt = 0; mt < m; mt++) tilemap[t++] = (e << 20) | (run + mt * 128);
      int n2 = (m + 1) >> 1;
      for (int i2 = 0; i2 < n2; i2++) {
        int st = i2 * 256;
        if (st + 256 > pc) st = (pc >= 256) ? (pc - 256) : 0;
        tile256[t2] = (e << 20) | (run + st);
        int v = pc - st; valid256[t2] = (v < 256) ? v : 256;
        t2++;
      }
      run += pc;
    }
    ctrl[24] = run; ctrl[25] = t; ctrl[26] = t2;
  }
  __syncthreads();
#pragma unroll
  for (int e = 0; e < NE; e++) {
    int c = h[e], pc = (c + 127) & ~127;
    for (int i = c + tid; i < pc; i += 256) tok[off[e] + i] = -1;
  }
  if (tid < NE) cnt[tid] = off[tid];
  __syncthreads();
  for (int i = tid; i < TOKENS * 2; i += 256) {
    int e = topki[i];
    int p = atomicAdd(&cnt[e], 1);
    tok[p] = i >> 1;
    slots[i] = p;
  }
}

// --------------- GEMM1: h = gather(xb) @ w1^T, silu(gate)*up -> a ----------
// EXACT round-0 version (measured 101 us / 30% MfmaUtil / 0 conflicts).
__global__ __launch_bounds__(256) void k_gemm1(
    const unsigned short* __restrict__ xb, const unsigned short* __restrict__ w1d,
    const int* __restrict__ ctrl, const int* __restrict__ tilemap,
    const int* __restrict__ tok, unsigned short* __restrict__ a_out) {
  __shared__ unsigned short sA[128 * 32];   // 8 KB
  __shared__ unsigned short sBg[64 * 32];   // 4 KB
  __shared__ unsigned short sBu[64 * 32];   // 4 KB
  int bid = blockIdx.x, tid = threadIdx.x;
  int nt = bid & 31, tile = bid >> 5;
  if (tile >= ctrl[25]) return;
  int tm = tilemap[tile];
  int e = tm >> 20, row0 = tm & 0xFFFFF;
  int n0 = nt * 64;
  int wave = tid >> 6, lane = tid & 63;
  int ln = lane & 15, quad = lane >> 4;
  int wr = (wave & 1) * 64, wc = (wave >> 1) * 32;

  int srow = tid >> 2, scblk = tid & 3;
  int scol = (scblk ^ ((srow >> 1) & 3)) * 8;
  int t0 = tok[row0 + srow];
  int t1 = tok[row0 + 64 + srow];
  const unsigned short* gA0 = xb + (size_t)(t0 < 0 ? TOKENS : t0) * HIDDEN + scol;
  const unsigned short* gA1 = xb + (size_t)(t1 < 0 ? TOKENS : t1) * HIDDEN + scol;
  const unsigned short* gBg = w1d + ((size_t)e * 4096 + n0 + srow) * HIDDEN + scol;
  const unsigned short* gBu = gBg + (size_t)INTER * HIDDEN;
  unsigned short* lA0 = sA + tid * 8;
  unsigned short* lA1 = sA + 64 * 32 + tid * 8;
  unsigned short* lBg = sBg + tid * 8;
  unsigned short* lBu = sBu + tid * 8;

  f32x4 aG[4][2] = {}, aU[4][2] = {};
  for (int k0 = 0; k0 < HIDDEN; k0 += 32) {
    __syncthreads();
    gload16(gA0 + k0, lA0);
    gload16(gA1 + k0, lA1);
    gload16(gBg + k0, lBg);
    gload16(gBu + k0, lBu);
    __syncthreads();
    bf16x8 af[4], bg[2], bu[2];
#pragma unroll
    for (int m = 0; m < 4; m++) {
      int ar = wr + m * 16 + ln;
      af[m] = *reinterpret_cast<const bf16x8*>(&sA[ar * 32 + (quad ^ ((ar >> 1) & 3)) * 8]);
    }
#pragma unroll
    for (int n = 0; n < 2; n++) {
      int br = wc + n * 16 + ln;
      int bo = br * 32 + (quad ^ ((br >> 1) & 3)) * 8;
      bg[n] = *reinterpret_cast<const bf16x8*>(&sBg[bo]);
      bu[n] = *reinterpret_cast<const bf16x8*>(&sBu[bo]);
    }
#pragma unroll
    for (int m = 0; m < 4; m++)
#pragma unroll
      for (int n = 0; n < 2; n++) {
        aG[m][n] = __builtin_amdgcn_mfma_f32_16x16x32_bf16(af[m], bg[n], aG[m][n], 0, 0, 0);
        aU[m][n] = __builtin_amdgcn_mfma_f32_16x16x32_bf16(af[m], bu[n], aU[m][n], 0, 0, 0);
      }
  }
#pragma unroll
  for (int m = 0; m < 4; m++)
#pragma unroll
    for (int n = 0; n < 2; n++) {
      int col = n0 + wc + n * 16 + ln;
#pragma unroll
      for (int r = 0; r < 4; r++) {
        float g = aG[m][n][r], u = aU[m][n][r];
        float act = (g / (1.f + __expf(-g))) * u;
        int row = row0 + wr + m * 16 + quad * 4 + r;
        a_out[(size_t)row * INTER + col] = f2bf(act);
      }
    }
}

// ------- GEMM2 split-K x2: y[kp][slot] = a[:,kp*1024:+1024] @ w2^T ---------
// EXACT round-0 version.
__global__ __launch_bounds__(256) void k_gemm2(
    const unsigned short* __restrict__ a_in, const unsigned short* __restrict__ w2d,
    const int* __restrict__ ctrl, const int* __restrict__ tilemap,
    unsigned short* __restrict__ y) {
  __shared__ unsigned short sA[128 * 32];   // 8 KB
  __shared__ unsigned short sB[128 * 32];   // 8 KB
  int bid = blockIdx.x, tid = threadIdx.x;
  int kp = bid & 1, nt = (bid >> 1) & 7, tile = bid >> 4;
  if (tile >= ctrl[25]) return;
  int tm = tilemap[tile];
  int e = tm >> 20, row0 = tm & 0xFFFFF;
  int n0 = nt * 128;
  int wave = tid >> 6, lane = tid & 63;
  int ln = lane & 15, quad = lane >> 4;
  int wr = (wave & 1) * 64, wc = (wave >> 1) * 64;

  int srow = tid >> 2, scblk = tid & 3;
  int scol = (scblk ^ ((srow >> 1) & 3)) * 8;
  int kbase = kp * (INTER / 2);
  const unsigned short* gA0 = a_in + (size_t)(row0 + srow) * INTER + kbase + scol;
  const unsigned short* gA1 = gA0 + (size_t)64 * INTER;
  const unsigned short* gB0 = w2d + ((size_t)e * 1024 + n0 + srow) * INTER + kbase + scol;
  const unsigned short* gB1 = gB0 + (size_t)64 * INTER;
  unsigned short* lA0 = sA + tid * 8;
  unsigned short* lA1 = sA + 64 * 32 + tid * 8;
  unsigned short* lB0 = sB + tid * 8;
  unsigned short* lB1 = sB + 64 * 32 + tid * 8;

  f32x4 acc[4][4] = {};
  for (int k0 = 0; k0 < INTER / 2; k0 += 32) {
    __syncthreads();
    gload16(gA0 + k0, lA0);
    gload16(gA1 + k0, lA1);
    gload16(gB0 + k0, lB0);
    gload16(gB1 + k0, lB1);
    __syncthreads();
    bf16x8 af[4], bf_[4];
#pragma unroll
    for (int m = 0; m < 4; m++) {
      int ar = wr + m * 16 + ln;
      af[m] = *reinterpret_cast<const bf16x8*>(&sA[ar * 32 + (quad ^ ((ar >> 1) & 3)) * 8]);
    }
#pragma unroll
    for (int n = 0; n < 4; n++) {
      int br = wc + n * 16 + ln;
      bf_[n] = *reinterpret_cast<const bf16x8*>(&sB[br * 32 + (quad ^ ((br >> 1) & 3)) * 8]);
    }
#pragma unroll
    for (int m = 0; m < 4; m++)
#pragma unroll
      for (int n = 0; n < 4; n++)
        acc[m][n] = __builtin_amdgcn_mfma_f32_16x16x32_bf16(af[m], bf_[n], acc[m][n], 0, 0, 0);
  }
  unsigned short* yk = y + (size_t)kp * MAXROWS * HIDDEN;
#pragma unroll
  for (int m = 0; m < 4; m++)
#pragma unroll
    for (int n = 0; n < 4; n++) {
      int col = n0 + wc + n * 16 + ln;
#pragma unroll
      for (int r = 0; r < 4; r++) {
        int row = row0 + wr + m * 16 + quad * 4 + r;
        yk[(size_t)row * HIDDEN + col] = f2bf(acc[m][n][r]);
      }
    }
}

// ------- combine: out[t] = g0*(y0[s0]+y1[s0]) + g1*(y0[s1]+y1[s1]) ---------
__global__ __launch_bounds__(256) void k_combine(const unsigned short* __restrict__ y,
    const int* __restrict__ slots, const float* __restrict__ topkw,
    float* __restrict__ out) {
  int t = blockIdx.x;
  int c = threadIdx.x * 4;
  int s0 = slots[t * 2], s1 = slots[t * 2 + 1];
  float g0 = topkw[t * 2], g1 = topkw[t * 2 + 1];
  const unsigned short* y1 = y + (size_t)MAXROWS * HIDDEN;
  uint2 a0 = *reinterpret_cast<const uint2*>(y  + (size_t)s0 * HIDDEN + c);
  uint2 a1 = *reinterpret_cast<const uint2*>(y1 + (size_t)s0 * HIDDEN + c);
  uint2 b0 = *reinterpret_cast<const uint2*>(y  + (size_t)s1 * HIDDEN + c);
  uint2 b1 = *reinterpret_cast<const uint2*>(y1 + (size_t)s1 * HIDDEN + c);
  float4 o;
  o.x = g0 * (bf2f(a0.x & 0xffffu) + bf2f(a1.x & 0xffffu))
      + g1 * (bf2f(b0.x & 0xffffu) + bf2f(b1.x & 0xffffu));
  o.y = g0 * (bf2f(a0.x >> 16) + bf2f(a1.x >> 16))
      + g1 * (bf2f(b0.x >> 16) + bf2f(b1.x >> 16));
  o.z = g0 * (bf2f(a0.y & 0xffffu) + bf2f(a1.y & 0xffffu))
      + g1 * (bf2f(b0.y & 0xffffu) + bf2f(b1.y & 0xffffu));
  o.w = g0 * (bf2f(a0.y >> 16) + bf2f(a1.y >> 16))
      + g1 * (bf2f(b0.y >> 16) + bf2f(b1.y >> 16));
  *reinterpret_cast<float4*>(out + (size_t)t * HIDDEN + c) = o;
}

extern "C" void kernel_launch(void* const* d_in, const int* in_sizes, int n_in,
                              void* d_out, int out_size, void* d_ws, size_t ws_size,
                              hipStream_t stream) {
  const float* x   = (const float*)d_in[0];
  const float* rw  = (const float*)d_in[1];
  const int*   w1  = (const int*)d_in[2];
  const float* w1s = (const float*)d_in[3];
  const int*   w2  = (const int*)d_in[4];
  const float* w2s = (const float*)d_in[5];
  float* out = (float*)d_out;
  char* ws = (char*)d_ws;

  int*   topki = (int*)(ws + OFF_TOPKI);
  float* topkw = (float*)(ws + OFF_TOPKW);
  int*   ctrl  = (int*)(ws + OFF_CTRL);
  int*   tok   = (int*)(ws + OFF_TOK);
  int*   slots = (int*)(ws + OFF_SLOT);
  int*   tilemap = (int*)(ws + OFF_TILE);
  int*   tile256 = (int*)(ws + OFF_T256);
  int*   valid256 = (int*)(ws + OFF_V256);
  unsigned short* xb  = (unsigned short*)(ws + OFF_XB);
  unsigned short* a   = (unsigned short*)(ws + OFF_A);
  unsigned short* w1d = (unsigned short*)(ws + OFF_W1D);
  unsigned short* w2d = (unsigned short*)(ws + OFF_W2D);
  unsigned short* y   = (unsigned short*)(ws + OFF_Y0);  // y1 = y + MAXROWS*HIDDEN

  k_prep<<<7169, 256, 0, stream>>>(x, rw, topki, topkw, w1, w1s, w1d, w2, w2s, w2d, xb);
  k_route2<<<1, 256, 0, stream>>>(topki, ctrl, tok, slots, tilemap, tile256, valid256);
  k_gemm1<<<32 * MAXTILES, 256, 0, stream>>>(xb, w1d, ctrl, tilemap, tok, a);
  k_gemm2<<<16 * MAXTILES, 256, 0, stream>>>(a, w2d, ctrl, tilemap, y);
  k_combine<<<TOKENS, 256, 0, stream>>>(y, slots, topkw, out);
}